// Round 14
// baseline (155.874 us; speedup 1.0000x reference)
//
#include <hip/hip_runtime.h>
#include <math.h>

#define NB 2
#define NPTS 4096
#define NQ 16384
#define QTOT (NB * NQ)   // 32768 queries, batch folded into row index
#define FCATC 448        // 64+128+256 concatenated feature channels per point

typedef _Float16 h8 __attribute__((ext_vector_type(8)));
typedef _Float16 h4 __attribute__((ext_vector_type(4)));
typedef float v4f __attribute__((ext_vector_type(4)));

// ---------------- k_pre: weight casts + GM zero + knn A-table build (R13 verbatim) ------
__global__ __launch_bounds__(256) void k_pre(
        const float* __restrict__ r1, const float* __restrict__ r2,
        const float* __restrict__ r3, const float* __restrict__ w2,
        const float* __restrict__ w3, const float* __restrict__ opts,
        _Float16* __restrict__ Rw1, _Float16* __restrict__ Rw2,
        _Float16* __restrict__ Rw3, _Float16* __restrict__ Ew2,
        _Float16* __restrict__ Ew3, _Float16* __restrict__ Atab,
        float* __restrict__ GM) {
    int blk = blockIdx.x;
    int t = threadIdx.x;
    if (blk < 768) {
        int g = blk * 256 + t;
        if (g < 114688) {                       // Rw1 = r1[:,3:451] (256 x 448)
            int o = g / FCATC, k = g - o * FCATC;
            Rw1[g] = (_Float16)r1[(size_t)o * 707 + 3 + k];
        } else if (g < 147456) {                // Rw2 = r2 (128x256)
            int i = g - 114688;
            Rw2[i] = (_Float16)r2[i];
        } else if (g < 155648) {                // Rw3 = r3 (64x128)
            int i = g - 147456;
            Rw3[i] = (_Float16)r3[i];
        } else if (g < 163840) {                // Ew2 = w2 (128x64)
            int i = g - 155648;
            Ew2[i] = (_Float16)w2[i];
        } else {                                // Ew3 = w3 (256x128)
            int i = g - 163840;
            Ew3[i] = (_Float16)w3[i];
        }
    } else if (blk == 768) {
        GM[t] = 0.f;
        GM[256 + t] = 0.f;
    } else {                                    // blocks 769..800: Atab (8192 points)
        int gi = (blk - 769) * 256 + t;
        int bb = gi >> 12, pp = gi & (NPTS - 1);
        const float* ob = opts + (size_t)bb * 3 * NPTS;
        float x = ob[pp], y = ob[NPTS + pp], z = ob[2 * NPTS + pp];
        float o2 = __fadd_rn(__fadd_rn(__fmul_rn(x, x), __fmul_rn(y, y)), __fmul_rn(z, z));
        _Float16 xh = (_Float16)x, yh = (_Float16)y, zh = (_Float16)z;
        _Float16 xl = (_Float16)(x - (float)xh);
        _Float16 yl = (_Float16)(y - (float)yh);
        _Float16 zl = (_Float16)(z - (float)zh);
        _Float16 o2h = (_Float16)o2;
        _Float16 o2l = (_Float16)(o2 - (float)o2h);
        _Float16 nxh = (_Float16)(-2.f * (float)xh);   // exact pow2 scale
        _Float16 nyh = (_Float16)(-2.f * (float)yh);
        _Float16 nzh = (_Float16)(-2.f * (float)zh);
        _Float16 nxl = (_Float16)(-2.f * (float)xl);
        _Float16 nyl = (_Float16)(-2.f * (float)yl);
        _Float16 nzl = (_Float16)(-2.f * (float)zl);
        _Float16 one = (_Float16)1.f, zero = (_Float16)0.f;
        h8 v0, v1;
        v0[0] = nxh; v0[1] = nyh; v0[2] = nzh; v0[3] = nxl;
        v0[4] = nyl; v0[5] = nzl; v0[6] = nxh; v0[7] = nyh;
        v1[0] = nzh; v1[1] = o2h; v1[2] = o2l; v1[3] = one;
        v1[4] = one; v1[5] = zero; v1[6] = zero; v1[7] = zero;
        _Float16* dst = Atab + (size_t)gi * 16;
        *(h8*)dst = v0;
        *(h8*)(dst + 8) = v1;
    }
}

// ---------------- k_fe: fused l1+l2+l3+max+G-GEMM, 16 pts/block x 512 blocks ------------
// R12 occupancy geometry (LDS ~46 KB -> 3 blocks/CU) + R13 staged pre-cast f16 weights.
// Same per-point MFMA operands and kc order as both verified parents -> bit-exact.
__global__ __launch_bounds__(256) void k_fe(const float* __restrict__ pts,
        const float* __restrict__ w1, const float* __restrict__ b1,
        const _Float16* __restrict__ Ew2, const float* __restrict__ b2,
        const _Float16* __restrict__ Ew3, const float* __restrict__ b3,
        const _Float16* __restrict__ Rw1, _Float16* __restrict__ G,
        unsigned* __restrict__ GM) {
    __shared__ __align__(16) unsigned char arena[43776];
    _Float16* sF1  = (_Float16*)arena;             // [16][72]  = 2304 B
    _Float16* sF2  = (_Float16*)(arena + 2304);    // [16][136] = 4352 B
    _Float16* sF3  = (_Float16*)(arena + 6656);    // [16][264] = 8448 B
    _Float16* sBst = (_Float16*)(arena + 15104);   // [256][56] = 28672 B
    __shared__ float sW1[192];
    __shared__ float sB1[64];
    __shared__ unsigned smax[256];
    int t = threadIdx.x;
    int w = t >> 6, lane = t & 63;
    int m = lane & 15, quad = lane >> 4;
    int wn = w;                     // 4 waves split the N (channel) dimension
    int P0 = blockIdx.x * 16;
    int bb = P0 >> 12;
    int p0in = P0 & (NPTS - 1);

    if (t < 192) sW1[t] = w1[t];
    if (t < 64)  sB1[t] = b1[t];
    smax[t] = 0u;
    __syncthreads();

    // ---- l1: f1 = relu(W1 @ pts + b1) -> sF1 (16 pts, 4 ch/thread) ----
    {
        int pt = t >> 4;
        int cs = (t & 15) * 4;
        const float* pb = pts + (size_t)bb * 3 * NPTS + p0in;
        float px = pb[pt], py = pb[NPTS + pt], pz = pb[2 * NPTS + pt];
        #pragma unroll
        for (int c = cs; c < cs + 4; c++) {
            float v = fmaf(sW1[c*3+0], px,
                      fmaf(sW1[c*3+1], py,
                      fmaf(sW1[c*3+2], pz, sB1[c])));
            sF1[pt * 72 + c] = (_Float16)fmaxf(v, 0.f);
        }
    }

    // ---- l2: f2(16pt x 128ch) = relu(Ew2 @ f1 + b2) -> sF2; wave wn owns 32 ch ----
    {
        v4f acc[2];
        acc[0] = (v4f){0.f, 0.f, 0.f, 0.f};
        acc[1] = (v4f){0.f, 0.f, 0.f, 0.f};
        for (int kc = 0; kc < 64; kc += 32) {
            __syncthreads();    // first iter: covers sF1 writes; later: sBst reuse
            #pragma unroll
            for (int i = 0; i < 2; i++) {       // 128 rows x 4 segs = 512; 2/thread
                int e = t + i * 256;
                int r = e >> 2, p = e & 3;
                *(float4*)&sBst[r * 56 + p * 8] =
                    *(const float4*)&Ew2[(size_t)r * 64 + kc + p * 8];
            }
            __syncthreads();
            h8 af = *(const h8*)&sF1[m * 72 + kc + quad * 8];
            #pragma unroll
            for (int nt = 0; nt < 2; nt++) {
                h8 bf = *(const h8*)&sBst[(wn * 32 + nt * 16 + m) * 56 + quad * 8];
                acc[nt] = __builtin_amdgcn_mfma_f32_16x16x32_f16(af, bf, acc[nt], 0, 0, 0);
            }
        }
        #pragma unroll
        for (int nt = 0; nt < 2; nt++) {
            int ch = wn * 32 + nt * 16 + m;
            float bb2 = b2[ch];
            #pragma unroll
            for (int r = 0; r < 4; r++) {
                int ptl = quad * 4 + r;
                sF2[ptl * 136 + ch] = (_Float16)fmaxf(acc[nt][r] + bb2, 0.f);
            }
        }
    }

    // ---- l3: f3(16pt x 256ch) = relu(Ew3 @ f2 + b3) -> sF3 + max; wave wn owns 64 ch ----
    {
        v4f acc[4];
        #pragma unroll
        for (int j = 0; j < 4; j++) acc[j] = (v4f){0.f, 0.f, 0.f, 0.f};
        for (int kc = 0; kc < 128; kc += 32) {
            __syncthreads();    // first iter: covers sF2 writes; later: sBst reuse
            #pragma unroll
            for (int i = 0; i < 4; i++) {       // 256 rows x 4 segs = 1024; 4/thread
                int e = t + i * 256;
                int r = e >> 2, p = e & 3;
                *(float4*)&sBst[r * 56 + p * 8] =
                    *(const float4*)&Ew3[(size_t)r * 128 + kc + p * 8];
            }
            __syncthreads();
            h8 af = *(const h8*)&sF2[m * 136 + kc + quad * 8];
            #pragma unroll
            for (int nt = 0; nt < 4; nt++) {
                h8 bf = *(const h8*)&sBst[(wn * 64 + nt * 16 + m) * 56 + quad * 8];
                acc[nt] = __builtin_amdgcn_mfma_f32_16x16x32_f16(af, bf, acc[nt], 0, 0, 0);
            }
        }
        #pragma unroll
        for (int nt = 0; nt < 4; nt++) {
            int ch = wn * 64 + nt * 16 + m;
            float bb3 = b3[ch];
            float vmax = 0.f;
            #pragma unroll
            for (int r = 0; r < 4; r++) {
                int ptl = quad * 4 + r;
                float v = fmaxf(acc[nt][r] + bb3, 0.f);
                vmax = fmaxf(vmax, v);
                sF3[ptl * 264 + ch] = (_Float16)v;
            }
            atomicMax(&smax[ch], __float_as_uint(vmax));
        }
        __syncthreads();
        atomicMax(GM + bb * 256 + t, smax[t]);
    }

    // ---- G-GEMM: G[16pt][256] = Rw1[256x448] @ [sF1|sF2|sF3]; wave wn owns 64 ch ----
    {
        v4f acc[4];
        #pragma unroll
        for (int j = 0; j < 4; j++) acc[j] = (v4f){0.f, 0.f, 0.f, 0.f};
        #pragma unroll
        for (int kc = 0; kc < FCATC; kc += 32) {
            __syncthreads();    // sBst reuse
            #pragma unroll
            for (int i = 0; i < 4; i++) {       // 256 rows x 4 segs = 1024; 4/thread
                int e = t + i * 256;
                int r = e >> 2, p = e & 3;
                *(float4*)&sBst[r * 56 + p * 8] =
                    *(const float4*)&Rw1[(size_t)r * FCATC + kc + p * 8];
            }
            __syncthreads();
            h8 af;
            if (kc < 64)
                af = *(const h8*)&sF1[m * 72 + kc + quad * 8];
            else if (kc < 192)
                af = *(const h8*)&sF2[m * 136 + (kc - 64) + quad * 8];
            else
                af = *(const h8*)&sF3[m * 264 + (kc - 192) + quad * 8];
            #pragma unroll
            for (int nt = 0; nt < 4; nt++) {
                h8 bf = *(const h8*)&sBst[(wn * 64 + nt * 16 + m) * 56 + quad * 8];
                acc[nt] = __builtin_amdgcn_mfma_f32_16x16x32_f16(af, bf, acc[nt], 0, 0, 0);
            }
        }
        #pragma unroll
        for (int nt = 0; nt < 4; nt++) {
            int ch = wn * 64 + nt * 16 + m;
            #pragma unroll
            for (int r = 0; r < 4; r++) {
                int ptl = quad * 4 + r;
                G[(size_t)(P0 + ptl) * 256 + ch] = (_Float16)acc[nt][r];
            }
        }
    }
}

// ---------------- KNN: K=16 MFMA + trimmed branchless packed-key top-3 (R13 verbatim) ---
#define LEXLT(dx, ix, dy, iy) ((dx) < (dy) || ((dx) == (dy) && (ix) < (iy)))
__global__ __launch_bounds__(512) void k_knn(const float* __restrict__ opts,
        const float* __restrict__ qpts, const _Float16* __restrict__ Atab,
        int* __restrict__ knn_idx, float* __restrict__ knn_w,
        const float* __restrict__ r1, const float* __restrict__ rb1,
        const float* __restrict__ gm, float* __restrict__ cb) {
    __shared__ float scr[256];
    __shared__ float md_s[8][16][4];
    __shared__ int   mi_s[8][16][4];
    int t = threadIdx.x;
    int blk = blockIdx.x;
    int b = blk >> 9;                   // 512 blocks per batch
    int q0b = (blk & 511) * 32;         // 32 queries per block
    // ---- CB rider: blocks 0..511 each compute one cb[o_global = blk] ----
    if (blk < 512) {
        int br = blk >> 8, o = blk & 255;
        if (t < 256) scr[t] = r1[(size_t)o * 707 + 451 + t] * gm[br * 256 + t];
        __syncthreads();
        if (t < 64) {
            float s = (scr[t] + scr[t + 64]) + (scr[t + 128] + scr[t + 192]);
            #pragma unroll
            for (int off = 32; off > 0; off >>= 1) s += __shfl_down(s, off);
            if (t == 0) cb[br * 256 + o] = rb1[o] + s;
        }
    }
    // ---- per-lane setup ----
    int w = t >> 6, l = t & 63;
    int g = l >> 4;                     // lane group (k-chunk / C-row group)
    int tw = w >> 2;                    // query tile within block (0/1)
    int qtr = w & 3;                    // point quarter
    int qcol = q0b + tw * 16 + (l & 15);
    const float* qb = qpts + (size_t)b * 3 * NQ;
    float qx = qb[qcol], qy = qb[NQ + qcol], qz = qb[2 * NQ + qcol];
    float q2 = __fadd_rn(__fadd_rn(__fmul_rn(qx, qx), __fmul_rn(qy, qy)), __fmul_rn(qz, qz));
    h4 bq;
    {
        _Float16 qh0 = (_Float16)qx, qh1 = (_Float16)qy, qh2 = (_Float16)qz;
        _Float16 ql0 = (_Float16)(qx - (float)qh0);
        _Float16 ql1 = (_Float16)(qy - (float)qh1);
        _Float16 ql2 = (_Float16)(qz - (float)qh2);
        _Float16 q2h = (_Float16)q2;
        _Float16 q2lo = (_Float16)(q2 - (float)q2h);
        _Float16 one = (_Float16)1.f, zero = (_Float16)0.f;
        if (g == 0)      { bq[0] = qh0; bq[1] = qh1; bq[2] = qh2; bq[3] = qh0; }
        else if (g == 1) { bq[0] = qh1; bq[1] = qh2; bq[2] = ql0; bq[3] = ql1; }
        else if (g == 2) { bq[0] = ql2; bq[1] = one; bq[2] = one; bq[3] = q2h; }
        else             { bq[0] = q2lo; bq[1] = zero; bq[2] = zero; bq[3] = zero; }
    }
    v4f zacc = (v4f){0.f, 0.f, 0.f, 0.f};
    float s0k = 1e30f, s1k = 1e30f, s2k = 1e30f;
#define INS_PK(dv, lb) do {                                                    \
    _Pragma("unroll")                                                          \
    for (int r = 0; r < 4; r++) {                                              \
        unsigned kb = (__float_as_uint((dv)[r]) & 0xFFFFFF00u) | (unsigned)((lb) + r); \
        float kf = __uint_as_float(kb);                                        \
        s2k = __builtin_amdgcn_fmed3f(s1k, s2k, kf);                           \
        s1k = __builtin_amdgcn_fmed3f(s0k, s1k, kf);                           \
        s0k = fminf(s0k, kf);                                                  \
    } } while (0)
    const _Float16* ap = Atab + ((size_t)b * NPTS + qtr * 1024) * 16
                       + (size_t)(l & 15) * 16 + (size_t)g * 4;
    h4 a0 = *(const h4*)(ap + 0 * 256);
    h4 a1 = *(const h4*)(ap + 1 * 256);
    h4 a2 = *(const h4*)(ap + 2 * 256);
    h4 a3 = *(const h4*)(ap + 3 * 256);
    for (int tl = 0; tl < 64; tl += 4) {
        v4f dv0 = __builtin_amdgcn_mfma_f32_16x16x16f16(a0, bq, zacc, 0, 0, 0);
        v4f dv1 = __builtin_amdgcn_mfma_f32_16x16x16f16(a1, bq, zacc, 0, 0, 0);
        v4f dv2 = __builtin_amdgcn_mfma_f32_16x16x16f16(a2, bq, zacc, 0, 0, 0);
        v4f dv3 = __builtin_amdgcn_mfma_f32_16x16x16f16(a3, bq, zacc, 0, 0, 0);
        // unclamped prefetch: last iteration overreads <=3.5KB into the G buffer (unused)
        a0 = *(const h4*)(ap + (size_t)(tl + 4) * 256);
        a1 = *(const h4*)(ap + (size_t)(tl + 5) * 256);
        a2 = *(const h4*)(ap + (size_t)(tl + 6) * 256);
        a3 = *(const h4*)(ap + (size_t)(tl + 7) * 256);
        INS_PK(dv0, (tl + 0) * 4);
        INS_PK(dv1, (tl + 1) * 4);
        INS_PK(dv2, (tl + 2) * 4);
        INS_PK(dv3, (tl + 3) * 4);
    }
    int nb0 = qtr * 1024 + g * 4;
    unsigned kb0 = __float_as_uint(s0k), kb1 = __float_as_uint(s1k), kb2 = __float_as_uint(s2k);
    int lo0 = kb0 & 0xFF, lo1 = kb1 & 0xFF, lo2 = kb2 & 0xFF;
    float d0 = __uint_as_float(kb0 & 0xFFFFFF00u);
    float d1 = __uint_as_float(kb1 & 0xFFFFFF00u);
    float d2v = __uint_as_float(kb2 & 0xFFFFFF00u);
    int i0 = nb0 + (lo0 >> 2) * 16 + (lo0 & 3);
    int i1 = nb0 + (lo1 >> 2) * 16 + (lo1 & 3);
    int i2 = nb0 + (lo2 >> 2) * 16 + (lo2 & 3);
    float c0 = d0, c1 = d1, c2 = d2v, c3 = 1e30f;
    int   k0 = i0, k1 = i1, k2 = i2, k3 = 0x7fffffff;
#define INS4(dd, ii) do { float _d = (dd); int _i = (ii);                      \
    if (LEXLT(_d, _i, c3, k3)) {                                              \
        if (LEXLT(_d, _i, c2, k2)) { c3 = c2; k3 = k2;                        \
            if (LEXLT(_d, _i, c1, k1)) { c2 = c1; k2 = k1;                    \
                if (LEXLT(_d, _i, c0, k0)) { c1 = c0; k1 = k0; c0 = _d; k0 = _i; } \
                else { c1 = _d; k1 = _i; }                                    \
            } else { c2 = _d; k2 = _i; }                                      \
        } else { c3 = _d; k3 = _i; }                                          \
    } } while (0)
    {
        float e0 = __shfl_xor(d0, 16), e1 = __shfl_xor(d1, 16), e2 = __shfl_xor(d2v, 16);
        int   j0 = __shfl_xor(i0, 16), j1 = __shfl_xor(i1, 16), j2 = __shfl_xor(i2, 16);
        INS4(e0, j0); INS4(e1, j1); INS4(e2, j2);
    }
    {
        float e0 = __shfl_xor(c0, 32), e1 = __shfl_xor(c1, 32),
              e2 = __shfl_xor(c2, 32), e3 = __shfl_xor(c3, 32);
        int   j0 = __shfl_xor(k0, 32), j1 = __shfl_xor(k1, 32),
              j2 = __shfl_xor(k2, 32), j3 = __shfl_xor(k3, 32);
        INS4(e0, j0); INS4(e1, j1); INS4(e2, j2); INS4(e3, j3);
    }
    if (l < 16) {
        md_s[w][l][0] = c0; md_s[w][l][1] = c1; md_s[w][l][2] = c2; md_s[w][l][3] = c3;
        mi_s[w][l][0] = k0; mi_s[w][l][1] = k1; mi_s[w][l][2] = k2; mi_s[w][l][3] = k3;
    }
    __syncthreads();
    if ((w & 3) == 0) {
        int m16 = l & 15;
        #pragma unroll
        for (int pw = 1; pw < 4; pw++) {
            #pragma unroll
            for (int s = 0; s < 4; s++) {
                float dd = md_s[w + pw][m16][s];
                int ii = mi_s[w + pw][m16][s];
                INS4(dd, ii);
            }
        }
        const float* ob = opts + (size_t)b * 3 * NPTS;
        float t0 = 1e30f, t1 = 1e30f, t2 = 1e30f;
        int   u0 = 0x7fffffff, u1 = 0x7fffffff, u2 = 0x7fffffff;
#define INS3X(dd, ii) do { float _d = (dd); int _i = (ii);                     \
    if (LEXLT(_d, _i, t2, u2)) {                                              \
        if (LEXLT(_d, _i, t1, u1)) { t2 = t1; u2 = u1;                        \
            if (LEXLT(_d, _i, t0, u0)) { t1 = t0; u1 = u0; t0 = _d; u0 = _i; } \
            else { t1 = _d; u1 = _i; }                                        \
        } else { t2 = _d; u2 = _i; }                                          \
    } } while (0)
#define EXACTD(idx, dout) do { int _p = (idx);                                 \
    float px = ob[_p], py = ob[NPTS + _p], pz = ob[2 * NPTS + _p];             \
    float o2x = __fadd_rn(__fadd_rn(__fmul_rn(px, px), __fmul_rn(py, py)), __fmul_rn(pz, pz)); \
    float cr  = __fadd_rn(__fadd_rn(__fmul_rn(qx, px), __fmul_rn(qy, py)), __fmul_rn(qz, pz)); \
    dout = __fsub_rn(__fadd_rn(q2, o2x), __fmul_rn(2.f, cr)); } while (0)
        {
            float dx0, dx1, dx2, dx3;
            EXACTD(k0, dx0); EXACTD(k1, dx1); EXACTD(k2, dx2); EXACTD(k3, dx3);
            INS3X(dx0, k0); INS3X(dx1, k1); INS3X(dx2, k2); INS3X(dx3, k3);
        }
        if (l < 16) {
            int ids[3] = {u0, u1, u2};
            float rr[3];
            float s = 0.f;
            #pragma unroll
            for (int mm = 0; mm < 3; mm++) {
                int ii = ids[mm];
                float px = ob[ii], py = ob[NPTS + ii], pz = ob[2 * NPTS + ii];
                float dx = __fsub_rn(px, qx), dy = __fsub_rn(py, qy), dz = __fsub_rn(pz, qz);
                float dd = __fadd_rn(__fadd_rn(__fmul_rn(dx, dx), __fmul_rn(dy, dy)), __fmul_rn(dz, dz));
                float dist = sqrtf(dd);
                rr[mm] = 1.f / (__fadd_rn(dist, 1e-8f));
                s += rr[mm];
            }
            int basei = (b * NQ + qcol) * 3;
            #pragma unroll
            for (int mm = 0; mm < 3; mm++) {
                knn_idx[basei + mm] = ids[mm];
                knn_w[basei + mm]   = rr[mm] / s;
            }
        }
    }
}

// ---------------- k_tail: fused interp + r2 + r3 + r4, 32 q/block (R13 verbatim) --------
__global__ __launch_bounds__(256) void k_tail(
        const float* __restrict__ qpts, const _Float16* __restrict__ G,
        const float* __restrict__ CB, const int* __restrict__ knn_idx,
        const float* __restrict__ knn_w, const float* __restrict__ r1,
        const _Float16* __restrict__ Rw2, const float* __restrict__ rb2,
        const _Float16* __restrict__ Rw3, const float* __restrict__ rb3,
        const float* __restrict__ r4, const float* __restrict__ rb4,
        float* __restrict__ out) {
    __shared__ __align__(16) unsigned char arena[31232];
    _Float16* sH1  = (_Float16*)arena;             // [32][264] = 16896 B
    _Float16* sBst = (_Float16*)(arena + 16896);   // r2 B-stage [128][56] = 14336 B
    _Float16* sH2  = (_Float16*)arena;             // [32][136] = 8704 (aliases sH1)
    _Float16* sH3  = (_Float16*)(arena + 8704);    // [64ch][72] = 9216 (32 cols used)
    _Float16* sW3  = (_Float16*)(arena + 17920);   // r3 W-stage [64][56] = 7168
    __shared__ int   s_id[96];
    __shared__ float s_wt[96];
    __shared__ float s_qp[3][32];
    __shared__ float s_wq[3][256];
    __shared__ float s_cb[256];
    __shared__ float sw4[64];
    int t = threadIdx.x;
    int w = t >> 6, lane = t & 63;
    int m = lane & 15, quad = lane >> 4;
    int q0 = blockIdx.x * 32;
    int b = q0 >> 14;
    int qin = q0 & (NQ - 1);

    if (t < 96) {
        s_id[t] = knn_idx[q0 * 3 + t];
        s_wt[t] = knn_w[q0 * 3 + t];
        int d = t >> 5, j = t & 31;
        s_qp[d][j] = qpts[(size_t)b * 3 * NQ + d * NQ + qin + j];
    }
    s_wq[0][t] = r1[(size_t)t * 707 + 0];
    s_wq[1][t] = r1[(size_t)t * 707 + 1];
    s_wq[2][t] = r1[(size_t)t * 707 + 2];
    s_cb[t] = CB[b * 256 + t];
    if (t < 64) sw4[t] = r4[t];
    __syncthreads();

    // ---- interp: build h1 tile [32 q][256 ch] in LDS (same fmaf order as before) ----
    {
        int cg = (t & 31) * 8;
        int js = t >> 5;
        float wq0[8], wq1[8], wq2[8], cbv[8];
        #pragma unroll
        for (int u = 0; u < 8; u++) {
            wq0[u] = s_wq[0][cg + u];
            wq1[u] = s_wq[1][cg + u];
            wq2[u] = s_wq[2][cg + u];
            cbv[u] = s_cb[cg + u];
        }
        const _Float16* Gb = G + (size_t)b * NPTS * 256;
        #pragma unroll
        for (int jj = 0; jj < 4; jj++) {
            int j = js + jj * 8;
            int i0 = s_id[j * 3 + 0], i1 = s_id[j * 3 + 1], i2 = s_id[j * 3 + 2];
            float w0 = s_wt[j * 3 + 0], w1 = s_wt[j * 3 + 1], w2 = s_wt[j * 3 + 2];
            float qx = s_qp[0][j], qy = s_qp[1][j], qz = s_qp[2][j];
            h8 g0 = *(const h8*)&Gb[(size_t)i0 * 256 + cg];
            h8 g1 = *(const h8*)&Gb[(size_t)i1 * 256 + cg];
            h8 g2 = *(const h8*)&Gb[(size_t)i2 * 256 + cg];
            h8 hv;
            #pragma unroll
            for (int u = 0; u < 8; u++) {
                float acc = cbv[u];
                acc = fmaf(wq0[u], qx, acc);
                acc = fmaf(wq1[u], qy, acc);
                acc = fmaf(wq2[u], qz, acc);
                acc = fmaf(w0, (float)g0[u], acc);
                acc = fmaf(w1, (float)g1[u], acc);
                acc = fmaf(w2, (float)g2[u], acc);
                hv[u] = (_Float16)fmaxf(acc, 0.f);
            }
            *(h8*)&sH1[j * 264 + cg] = hv;
        }
    }

    // ---- r2: h2(32q x 128ch) = relu(Rw2 @ h1); A-frags straight from sH1 ----
    float h2v[2][2][4];
    {
        v4f acc[2][2];
        #pragma unroll
        for (int i = 0; i < 2; i++)
            #pragma unroll
            for (int j = 0; j < 2; j++)
                acc[i][j] = (v4f){0.f, 0.f, 0.f, 0.f};
        for (int kc = 0; kc < 256; kc += 32) {
            __syncthreads();   // first: sH1 writes; later: sBst reuse
            #pragma unroll
            for (int i = 0; i < 2; i++) {
                int e = t + i * 256;
                int r = e >> 2, p = e & 3;
                *(float4*)&sBst[r * 56 + p * 8] =
                    *(const float4*)&Rw2[(size_t)r * 256 + kc + p * 8];
            }
            __syncthreads();
            h8 af[2], bf[2];
            #pragma unroll
            for (int mt = 0; mt < 2; mt++)
                af[mt] = *(const h8*)&sH1[(mt * 16 + m) * 264 + kc + quad * 8];
            #pragma unroll
            for (int nt = 0; nt < 2; nt++)
                bf[nt] = *(const h8*)&sBst[(w * 32 + nt * 16 + m) * 56 + quad * 8];
            #pragma unroll
            for (int mt = 0; mt < 2; mt++)
                #pragma unroll
                for (int nt = 0; nt < 2; nt++)
                    acc[mt][nt] = __builtin_amdgcn_mfma_f32_16x16x32_f16(
                            af[mt], bf[nt], acc[mt][nt], 0, 0, 0);
        }
        #pragma unroll
        for (int nt = 0; nt < 2; nt++) {
            int ch = w * 32 + nt * 16 + m;
            float bb2 = rb2[ch];
            #pragma unroll
            for (int mt = 0; mt < 2; mt++)
                #pragma unroll
                for (int r = 0; r < 4; r++)
                    h2v[mt][nt][r] = fmaxf(acc[mt][nt][r] + bb2, 0.f);
        }
    }
    __syncthreads();   // all sH1 reads done -> safe to overwrite with sH2
    {
        #pragma unroll
        for (int nt = 0; nt < 2; nt++) {
            int ch = w * 32 + nt * 16 + m;
            #pragma unroll
            for (int mt = 0; mt < 2; mt++)
                #pragma unroll
                for (int r = 0; r < 4; r++) {
                    int ql = mt * 16 + quad * 4 + r;
                    sH2[ql * 136 + ch] = (_Float16)h2v[mt][nt][r];
                }
        }
    }

    // ---- r3: h3(32q x 64ch) = relu(Rw3 @ h2) ----
    float h3v[2][4];
    {
        v4f acc[2];
        acc[0] = (v4f){0.f, 0.f, 0.f, 0.f};
        acc[1] = (v4f){0.f, 0.f, 0.f, 0.f};
        for (int kc = 0; kc < 128; kc += 32) {
            __syncthreads();   // first: sH2 writes; later: sW3 reuse
            {   // 64 rows x 4 segs = 256; 1 per thread
                int r = t >> 2, p = t & 3;
                *(float4*)&sW3[r * 56 + p * 8] =
                    *(const float4*)&Rw3[(size_t)r * 128 + kc + p * 8];
            }
            __syncthreads();
            h8 af[2], bf;
            #pragma unroll
            for (int mt = 0; mt < 2; mt++)
                af[mt] = *(const h8*)&sH2[(mt * 16 + m) * 136 + kc + quad * 8];
            bf = *(const h8*)&sW3[(w * 16 + m) * 56 + quad * 8];
            #pragma unroll
            for (int mt = 0; mt < 2; mt++)
                acc[mt] = __builtin_amdgcn_mfma_f32_16x16x32_f16(
                        af[mt], bf, acc[mt], 0, 0, 0);
        }
        int ch = w * 16 + m;
        float bb3 = rb3[ch];
        #pragma unroll
        for (int mt = 0; mt < 2; mt++)
            #pragma unroll
            for (int r = 0; r < 4; r++)
                h3v[mt][r] = fmaxf(acc[mt][r] + bb3, 0.f);
    }
    __syncthreads();
    {
        int ch = w * 16 + m;
        #pragma unroll
        for (int mt = 0; mt < 2; mt++)
            #pragma unroll
            for (int r = 0; r < 4; r++) {
                int ql = mt * 16 + quad * 4 + r;
                sH3[ch * 72 + ql] = (_Float16)h3v[mt][r];
            }
    }
    __syncthreads();

    // ---- r4: out = r4 . h3 + rb4 ----
    if (t < 32) {
        float acc = rb4[0];
        #pragma unroll 16
        for (int c = 0; c < 64; c++)
            acc = fmaf((float)sH3[c * 72 + t], sw4[c], acc);
        out[q0 + t] = acc;
    }
}

extern "C" void kernel_launch(void* const* d_in, const int* in_sizes, int n_in,
                              void* d_out, int out_size, void* d_ws, size_t ws_size,
                              hipStream_t stream) {
    const float* opts = (const float*)d_in[0];
    const float* qpts = (const float*)d_in[1];
    const float* w1  = (const float*)d_in[2];
    const float* b1  = (const float*)d_in[3];
    const float* w2  = (const float*)d_in[4];
    const float* b2  = (const float*)d_in[5];
    const float* w3  = (const float*)d_in[6];
    const float* b3  = (const float*)d_in[7];
    const float* r1  = (const float*)d_in[8];
    const float* rb1 = (const float*)d_in[9];
    const float* r2  = (const float*)d_in[10];
    const float* rb2 = (const float*)d_in[11];
    const float* r3  = (const float*)d_in[12];
    const float* rb3 = (const float*)d_in[13];
    const float* r4  = (const float*)d_in[14];
    const float* rb4 = (const float*)d_in[15];
    float* out = (float*)d_out;

    unsigned char* p = (unsigned char*)d_ws;
    float* GM = (float*)p;          p += (size_t)NB * 256 * 4;
    float* CB = (float*)p;          p += (size_t)NB * 256 * 4;
    int*   IDX = (int*)p;           p += (size_t)NB * NQ * 3 * 4;
    float* WT = (float*)p;          p += (size_t)NB * NQ * 3 * 4;
    _Float16* Rw1 = (_Float16*)p;   p += (size_t)256 * FCATC * 2;
    _Float16* Rw2 = (_Float16*)p;   p += (size_t)128 * 256 * 2;
    _Float16* Rw3 = (_Float16*)p;   p += (size_t)64 * 128 * 2;
    _Float16* Ew2 = (_Float16*)p;   p += (size_t)128 * 64 * 2;
    _Float16* Ew3 = (_Float16*)p;   p += (size_t)256 * 128 * 2;
    _Float16* Atab = (_Float16*)p;  p += (size_t)NB * NPTS * 16 * 2;
    _Float16* G = (_Float16*)p;     p += (size_t)NB * NPTS * 256 * 2;   // prefetch slack

    k_pre<<<801, 256, 0, stream>>>(r1, r2, r3, w2, w3, opts,
                                   Rw1, Rw2, Rw3, Ew2, Ew3, Atab, GM);
    // fe: 16 pts/block x 512 blocks, staged pre-cast f16 weights (3 blocks/CU)
    k_fe<<<NB * NPTS / 16, 256, 0, stream>>>(opts, w1, b1, Ew2, b2, Ew3, b3,
                                             Rw1, G, (unsigned*)GM);
    // K=16 MFMA knn, trimmed branchless packed-key selection; 1024 blocks x 512 thr
    k_knn<<<1024, 512, 0, stream>>>(opts, qpts, Atab, IDX, WT, r1, rb1, GM, CB);
    // tail: 32 q/block x 1024 blocks, staged pre-cast Rw2/Rw3 (R7 structure)
    k_tail<<<QTOT / 32, 256, 0, stream>>>(qpts, G, CB, IDX, WT, r1,
                                          Rw2, rb2, Rw3, rb3, r4, rb4, out);
}

// Round 15
// 152.886 us; speedup vs baseline: 1.0195x; 1.0195x over previous
//
#include <hip/hip_runtime.h>
#include <math.h>

#define NB 2
#define NPTS 4096
#define NQ 16384
#define QTOT (NB * NQ)   // 32768 queries, batch folded into row index
#define FCATC 448        // 64+128+256 concatenated feature channels per point

typedef _Float16 h8 __attribute__((ext_vector_type(8)));
typedef _Float16 h4 __attribute__((ext_vector_type(4)));
typedef float v4f __attribute__((ext_vector_type(4)));

// ---------------- k_pre: weight casts + GM zero + knn A-table build (R13 verbatim) ------
__global__ __launch_bounds__(256) void k_pre(
        const float* __restrict__ r1, const float* __restrict__ r2,
        const float* __restrict__ r3, const float* __restrict__ w2,
        const float* __restrict__ w3, const float* __restrict__ opts,
        _Float16* __restrict__ Rw1, _Float16* __restrict__ Rw2,
        _Float16* __restrict__ Rw3, _Float16* __restrict__ Ew2,
        _Float16* __restrict__ Ew3, _Float16* __restrict__ Atab,
        float* __restrict__ GM) {
    int blk = blockIdx.x;
    int t = threadIdx.x;
    if (blk < 768) {
        int g = blk * 256 + t;
        if (g < 114688) {                       // Rw1 = r1[:,3:451] (256 x 448)
            int o = g / FCATC, k = g - o * FCATC;
            Rw1[g] = (_Float16)r1[(size_t)o * 707 + 3 + k];
        } else if (g < 147456) {                // Rw2 = r2 (128x256)
            int i = g - 114688;
            Rw2[i] = (_Float16)r2[i];
        } else if (g < 155648) {                // Rw3 = r3 (64x128)
            int i = g - 147456;
            Rw3[i] = (_Float16)r3[i];
        } else if (g < 163840) {                // Ew2 = w2 (128x64)
            int i = g - 155648;
            Ew2[i] = (_Float16)w2[i];
        } else {                                // Ew3 = w3 (256x128)
            int i = g - 163840;
            Ew3[i] = (_Float16)w3[i];
        }
    } else if (blk == 768) {
        GM[t] = 0.f;
        GM[256 + t] = 0.f;
    } else {                                    // blocks 769..800: Atab (8192 points)
        int gi = (blk - 769) * 256 + t;
        int bb = gi >> 12, pp = gi & (NPTS - 1);
        const float* ob = opts + (size_t)bb * 3 * NPTS;
        float x = ob[pp], y = ob[NPTS + pp], z = ob[2 * NPTS + pp];
        float o2 = __fadd_rn(__fadd_rn(__fmul_rn(x, x), __fmul_rn(y, y)), __fmul_rn(z, z));
        _Float16 xh = (_Float16)x, yh = (_Float16)y, zh = (_Float16)z;
        _Float16 xl = (_Float16)(x - (float)xh);
        _Float16 yl = (_Float16)(y - (float)yh);
        _Float16 zl = (_Float16)(z - (float)zh);
        _Float16 o2h = (_Float16)o2;
        _Float16 o2l = (_Float16)(o2 - (float)o2h);
        _Float16 nxh = (_Float16)(-2.f * (float)xh);   // exact pow2 scale
        _Float16 nyh = (_Float16)(-2.f * (float)yh);
        _Float16 nzh = (_Float16)(-2.f * (float)zh);
        _Float16 nxl = (_Float16)(-2.f * (float)xl);
        _Float16 nyl = (_Float16)(-2.f * (float)yl);
        _Float16 nzl = (_Float16)(-2.f * (float)zl);
        _Float16 one = (_Float16)1.f, zero = (_Float16)0.f;
        h8 v0, v1;
        v0[0] = nxh; v0[1] = nyh; v0[2] = nzh; v0[3] = nxl;
        v0[4] = nyl; v0[5] = nzl; v0[6] = nxh; v0[7] = nyh;
        v1[0] = nzh; v1[1] = o2h; v1[2] = o2l; v1[3] = one;
        v1[4] = one; v1[5] = zero; v1[6] = zero; v1[7] = zero;
        _Float16* dst = Atab + (size_t)gi * 16;
        *(h8*)dst = v0;
        *(h8*)(dst + 8) = v1;
    }
}

// ---------------- k_fe: fused l1+l2+l3+max+G-GEMM, 32 pts/block (R13 verbatim) ----------
__global__ __launch_bounds__(256) void k_fe(const float* __restrict__ pts,
        const float* __restrict__ w1, const float* __restrict__ b1,
        const _Float16* __restrict__ Ew2, const float* __restrict__ b2,
        const _Float16* __restrict__ Ew3, const float* __restrict__ b3,
        const _Float16* __restrict__ Rw1, _Float16* __restrict__ G,
        unsigned* __restrict__ GM) {
    __shared__ __align__(16) unsigned char arena[58880];
    _Float16* sF1  = (_Float16*)arena;             // [32][72]  = 4608 B
    _Float16* sF2  = (_Float16*)(arena + 4608);    // [32][136] = 8704 B
    _Float16* sF3  = (_Float16*)(arena + 13312);   // [32][264] = 16896 B
    _Float16* sBst = (_Float16*)(arena + 30208);   // [256][56] = 28672 B
    __shared__ float sW1[192];
    __shared__ float sB1[64];
    __shared__ unsigned smax[256];
    int t = threadIdx.x;
    int w = t >> 6, lane = t & 63;
    int m = lane & 15, quad = lane >> 4;
    int wq = w & 1, wn = w >> 1;   // wq: 16-row M half; wn: N half
    int P0 = blockIdx.x * 32;
    int bb = P0 >> 12;
    int p0in = P0 & (NPTS - 1);

    if (t < 192) sW1[t] = w1[t];
    if (t < 64)  sB1[t] = b1[t];
    smax[t] = 0u;
    __syncthreads();

    // ---- l1: f1 = relu(W1 @ pts + b1) -> sF1 (32 pts, 8 ch/thread) ----
    {
        int pt = t >> 3;
        int cs = (t & 7) * 8;
        const float* pb = pts + (size_t)bb * 3 * NPTS + p0in;
        float px = pb[pt], py = pb[NPTS + pt], pz = pb[2 * NPTS + pt];
        #pragma unroll 8
        for (int c = cs; c < cs + 8; c++) {
            float v = fmaf(sW1[c*3+0], px,
                      fmaf(sW1[c*3+1], py,
                      fmaf(sW1[c*3+2], pz, sB1[c])));
            sF1[pt * 72 + c] = (_Float16)fmaxf(v, 0.f);
        }
    }

    // ---- l2: f2(32pt x 128ch) = relu(Ew2 @ f1 + b2) -> sF2 ----
    {
        v4f acc[4];
        #pragma unroll
        for (int j = 0; j < 4; j++) acc[j] = (v4f){0.f, 0.f, 0.f, 0.f};
        for (int kc = 0; kc < 64; kc += 32) {
            __syncthreads();    // first iter: covers sF1 writes; later: sBst reuse
            #pragma unroll
            for (int i = 0; i < 2; i++) {       // 128 rows x 4 segs = 512; 2/thread
                int e = t + i * 256;
                int r = e >> 2, p = e & 3;
                *(float4*)&sBst[r * 56 + p * 8] =
                    *(const float4*)&Ew2[(size_t)r * 64 + kc + p * 8];
            }
            __syncthreads();
            h8 af = *(const h8*)&sF1[(wq * 16 + m) * 72 + kc + quad * 8];
            h8 bf[4];
            #pragma unroll
            for (int nt = 0; nt < 4; nt++)
                bf[nt] = *(const h8*)&sBst[(wn * 64 + nt * 16 + m) * 56 + quad * 8];
            #pragma unroll
            for (int nt = 0; nt < 4; nt++)
                acc[nt] = __builtin_amdgcn_mfma_f32_16x16x32_f16(af, bf[nt], acc[nt], 0, 0, 0);
        }
        #pragma unroll
        for (int nt = 0; nt < 4; nt++) {
            int ch = wn * 64 + nt * 16 + m;
            float bb2 = b2[ch];
            #pragma unroll
            for (int r = 0; r < 4; r++) {
                int ptl = wq * 16 + quad * 4 + r;
                sF2[ptl * 136 + ch] = (_Float16)fmaxf(acc[nt][r] + bb2, 0.f);
            }
        }
    }

    // ---- l3: f3(32pt x 256ch) = relu(Ew3 @ f2 + b3) -> sF3 + max ----
    {
        v4f acc[8];
        #pragma unroll
        for (int j = 0; j < 8; j++) acc[j] = (v4f){0.f, 0.f, 0.f, 0.f};
        for (int kc = 0; kc < 128; kc += 32) {
            __syncthreads();    // first iter: covers sF2 writes; later: sBst reuse
            #pragma unroll
            for (int i = 0; i < 4; i++) {       // 256 rows x 4 segs = 1024; 4/thread
                int e = t + i * 256;
                int r = e >> 2, p = e & 3;
                *(float4*)&sBst[r * 56 + p * 8] =
                    *(const float4*)&Ew3[(size_t)r * 128 + kc + p * 8];
            }
            __syncthreads();
            h8 af = *(const h8*)&sF2[(wq * 16 + m) * 136 + kc + quad * 8];
            h8 bf[8];
            #pragma unroll
            for (int nt = 0; nt < 8; nt++)
                bf[nt] = *(const h8*)&sBst[(wn * 128 + nt * 16 + m) * 56 + quad * 8];
            #pragma unroll
            for (int nt = 0; nt < 8; nt++)
                acc[nt] = __builtin_amdgcn_mfma_f32_16x16x32_f16(af, bf[nt], acc[nt], 0, 0, 0);
        }
        #pragma unroll
        for (int nt = 0; nt < 8; nt++) {
            int ch = wn * 128 + nt * 16 + m;
            float bb3 = b3[ch];
            float vmax = 0.f;
            #pragma unroll
            for (int r = 0; r < 4; r++) {
                int ptl = wq * 16 + quad * 4 + r;
                float v = fmaxf(acc[nt][r] + bb3, 0.f);
                vmax = fmaxf(vmax, v);
                sF3[ptl * 264 + ch] = (_Float16)v;
            }
            atomicMax(&smax[ch], __float_as_uint(vmax));
        }
        __syncthreads();
        atomicMax(GM + bb * 256 + t, smax[t]);
    }

    // ---- G-GEMM: G[32pt][256] = Rw1[256x448] @ [sF1|sF2|sF3], kc chunks of 32 ----
    {
        v4f acc[8];
        #pragma unroll
        for (int j = 0; j < 8; j++) acc[j] = (v4f){0.f, 0.f, 0.f, 0.f};
        #pragma unroll
        for (int kc = 0; kc < FCATC; kc += 32) {
            __syncthreads();    // sBst reuse
            #pragma unroll
            for (int i = 0; i < 4; i++) {       // 256 rows x 4 segs = 1024; 4/thread
                int e = t + i * 256;
                int r = e >> 2, p = e & 3;
                *(float4*)&sBst[r * 56 + p * 8] =
                    *(const float4*)&Rw1[(size_t)r * FCATC + kc + p * 8];
            }
            __syncthreads();
            int row = wq * 16 + m;
            h8 af;
            if (kc < 64)
                af = *(const h8*)&sF1[row * 72 + kc + quad * 8];
            else if (kc < 192)
                af = *(const h8*)&sF2[row * 136 + (kc - 64) + quad * 8];
            else
                af = *(const h8*)&sF3[row * 264 + (kc - 192) + quad * 8];
            h8 bf[8];
            #pragma unroll
            for (int nt = 0; nt < 8; nt++)
                bf[nt] = *(const h8*)&sBst[(wn * 128 + nt * 16 + m) * 56 + quad * 8];
            #pragma unroll
            for (int nt = 0; nt < 8; nt++)
                acc[nt] = __builtin_amdgcn_mfma_f32_16x16x32_f16(af, bf[nt], acc[nt], 0, 0, 0);
        }
        #pragma unroll
        for (int nt = 0; nt < 8; nt++) {
            int ch = wn * 128 + nt * 16 + m;
            #pragma unroll
            for (int r = 0; r < 4; r++) {
                int ptl = wq * 16 + quad * 4 + r;
                G[(size_t)(P0 + ptl) * 256 + ch] = (_Float16)acc[nt][r];
            }
        }
    }
}

// ---------------- KNN: K=16 MFMA + DUAL-CHAIN packed-key top-3 ----------------
// vs R13: the serial med3 insert chain is split into two independent chains (even/odd
// tiles) to double ILP on the latency-critical path, then chain B's 3 keys are
// sorted-inserted into chain A (total order on packed keys -> exact per-lane top-3 of
// the union -> identical candidate set -> bit-exact after exact re-rank).
#define LEXLT(dx, ix, dy, iy) ((dx) < (dy) || ((dx) == (dy) && (ix) < (iy)))
__global__ __launch_bounds__(512) void k_knn(const float* __restrict__ opts,
        const float* __restrict__ qpts, const _Float16* __restrict__ Atab,
        int* __restrict__ knn_idx, float* __restrict__ knn_w,
        const float* __restrict__ r1, const float* __restrict__ rb1,
        const float* __restrict__ gm, float* __restrict__ cb) {
    __shared__ float scr[256];
    __shared__ float md_s[8][16][4];
    __shared__ int   mi_s[8][16][4];
    int t = threadIdx.x;
    int blk = blockIdx.x;
    int b = blk >> 9;                   // 512 blocks per batch
    int q0b = (blk & 511) * 32;         // 32 queries per block
    // ---- CB rider: blocks 0..511 each compute one cb[o_global = blk] ----
    if (blk < 512) {
        int br = blk >> 8, o = blk & 255;
        if (t < 256) scr[t] = r1[(size_t)o * 707 + 451 + t] * gm[br * 256 + t];
        __syncthreads();
        if (t < 64) {
            float s = (scr[t] + scr[t + 64]) + (scr[t + 128] + scr[t + 192]);
            #pragma unroll
            for (int off = 32; off > 0; off >>= 1) s += __shfl_down(s, off);
            if (t == 0) cb[br * 256 + o] = rb1[o] + s;
        }
    }
    // ---- per-lane setup ----
    int w = t >> 6, l = t & 63;
    int g = l >> 4;                     // lane group (k-chunk / C-row group)
    int tw = w >> 2;                    // query tile within block (0/1)
    int qtr = w & 3;                    // point quarter
    int qcol = q0b + tw * 16 + (l & 15);
    const float* qb = qpts + (size_t)b * 3 * NQ;
    float qx = qb[qcol], qy = qb[NQ + qcol], qz = qb[2 * NQ + qcol];
    float q2 = __fadd_rn(__fadd_rn(__fmul_rn(qx, qx), __fmul_rn(qy, qy)), __fmul_rn(qz, qz));
    h4 bq;
    {
        _Float16 qh0 = (_Float16)qx, qh1 = (_Float16)qy, qh2 = (_Float16)qz;
        _Float16 ql0 = (_Float16)(qx - (float)qh0);
        _Float16 ql1 = (_Float16)(qy - (float)qh1);
        _Float16 ql2 = (_Float16)(qz - (float)qh2);
        _Float16 q2h = (_Float16)q2;
        _Float16 q2lo = (_Float16)(q2 - (float)q2h);
        _Float16 one = (_Float16)1.f, zero = (_Float16)0.f;
        if (g == 0)      { bq[0] = qh0; bq[1] = qh1; bq[2] = qh2; bq[3] = qh0; }
        else if (g == 1) { bq[0] = qh1; bq[1] = qh2; bq[2] = ql0; bq[3] = ql1; }
        else if (g == 2) { bq[0] = ql2; bq[1] = one; bq[2] = one; bq[3] = q2h; }
        else             { bq[0] = q2lo; bq[1] = zero; bq[2] = zero; bq[3] = zero; }
    }
    v4f zacc = (v4f){0.f, 0.f, 0.f, 0.f};
    float sA0 = 1e30f, sA1 = 1e30f, sA2 = 1e30f;   // chain A (even tiles)
    float sB0 = 1e30f, sB1 = 1e30f, sB2 = 1e30f;   // chain B (odd tiles)
#define INS_PKA(dv, lb) do {                                                   \
    _Pragma("unroll")                                                          \
    for (int r = 0; r < 4; r++) {                                              \
        unsigned kb = (__float_as_uint((dv)[r]) & 0xFFFFFF00u) | (unsigned)((lb) + r); \
        float kf = __uint_as_float(kb);                                        \
        sA2 = __builtin_amdgcn_fmed3f(sA1, sA2, kf);                           \
        sA1 = __builtin_amdgcn_fmed3f(sA0, sA1, kf);                           \
        sA0 = fminf(sA0, kf);                                                  \
    } } while (0)
#define INS_PKB(dv, lb) do {                                                   \
    _Pragma("unroll")                                                          \
    for (int r = 0; r < 4; r++) {                                              \
        unsigned kb = (__float_as_uint((dv)[r]) & 0xFFFFFF00u) | (unsigned)((lb) + r); \
        float kf = __uint_as_float(kb);                                        \
        sB2 = __builtin_amdgcn_fmed3f(sB1, sB2, kf);                           \
        sB1 = __builtin_amdgcn_fmed3f(sB0, sB1, kf);                           \
        sB0 = fminf(sB0, kf);                                                  \
    } } while (0)
    const _Float16* ap = Atab + ((size_t)b * NPTS + qtr * 1024) * 16
                       + (size_t)(l & 15) * 16 + (size_t)g * 4;
    h4 a0 = *(const h4*)(ap + 0 * 256);
    h4 a1 = *(const h4*)(ap + 1 * 256);
    h4 a2 = *(const h4*)(ap + 2 * 256);
    h4 a3 = *(const h4*)(ap + 3 * 256);
    for (int tl = 0; tl < 64; tl += 4) {
        v4f dv0 = __builtin_amdgcn_mfma_f32_16x16x16f16(a0, bq, zacc, 0, 0, 0);
        v4f dv1 = __builtin_amdgcn_mfma_f32_16x16x16f16(a1, bq, zacc, 0, 0, 0);
        v4f dv2 = __builtin_amdgcn_mfma_f32_16x16x16f16(a2, bq, zacc, 0, 0, 0);
        v4f dv3 = __builtin_amdgcn_mfma_f32_16x16x16f16(a3, bq, zacc, 0, 0, 0);
        // unclamped prefetch: last iteration overreads <=3.5KB into the G buffer (unused)
        a0 = *(const h4*)(ap + (size_t)(tl + 4) * 256);
        a1 = *(const h4*)(ap + (size_t)(tl + 5) * 256);
        a2 = *(const h4*)(ap + (size_t)(tl + 6) * 256);
        a3 = *(const h4*)(ap + (size_t)(tl + 7) * 256);
        INS_PKA(dv0, (tl + 0) * 4);
        INS_PKB(dv1, (tl + 1) * 4);
        INS_PKA(dv2, (tl + 2) * 4);
        INS_PKB(dv3, (tl + 3) * 4);
    }
    // merge chain B into chain A (packed keys form a total order)
    {
        sA2 = __builtin_amdgcn_fmed3f(sA1, sA2, sB0);
        sA1 = __builtin_amdgcn_fmed3f(sA0, sA1, sB0);
        sA0 = fminf(sA0, sB0);
        sA2 = __builtin_amdgcn_fmed3f(sA1, sA2, sB1);
        sA1 = __builtin_amdgcn_fmed3f(sA0, sA1, sB1);
        sA0 = fminf(sA0, sB1);
        sA2 = __builtin_amdgcn_fmed3f(sA1, sA2, sB2);
        sA1 = __builtin_amdgcn_fmed3f(sA0, sA1, sB2);
        sA0 = fminf(sA0, sB2);
    }
    int nb0 = qtr * 1024 + g * 4;
    unsigned kb0 = __float_as_uint(sA0), kb1 = __float_as_uint(sA1), kb2 = __float_as_uint(sA2);
    int lo0 = kb0 & 0xFF, lo1 = kb1 & 0xFF, lo2 = kb2 & 0xFF;
    float d0 = __uint_as_float(kb0 & 0xFFFFFF00u);
    float d1 = __uint_as_float(kb1 & 0xFFFFFF00u);
    float d2v = __uint_as_float(kb2 & 0xFFFFFF00u);
    int i0 = nb0 + (lo0 >> 2) * 16 + (lo0 & 3);
    int i1 = nb0 + (lo1 >> 2) * 16 + (lo1 & 3);
    int i2 = nb0 + (lo2 >> 2) * 16 + (lo2 & 3);
    float c0 = d0, c1 = d1, c2 = d2v, c3 = 1e30f;
    int   k0 = i0, k1 = i1, k2 = i2, k3 = 0x7fffffff;
#define INS4(dd, ii) do { float _d = (dd); int _i = (ii);                      \
    if (LEXLT(_d, _i, c3, k3)) {                                              \
        if (LEXLT(_d, _i, c2, k2)) { c3 = c2; k3 = k2;                        \
            if (LEXLT(_d, _i, c1, k1)) { c2 = c1; k2 = k1;                    \
                if (LEXLT(_d, _i, c0, k0)) { c1 = c0; k1 = k0; c0 = _d; k0 = _i; } \
                else { c1 = _d; k1 = _i; }                                    \
            } else { c2 = _d; k2 = _i; }                                      \
        } else { c3 = _d; k3 = _i; }                                          \
    } } while (0)
    {
        float e0 = __shfl_xor(d0, 16), e1 = __shfl_xor(d1, 16), e2 = __shfl_xor(d2v, 16);
        int   j0 = __shfl_xor(i0, 16), j1 = __shfl_xor(i1, 16), j2 = __shfl_xor(i2, 16);
        INS4(e0, j0); INS4(e1, j1); INS4(e2, j2);
    }
    {
        float e0 = __shfl_xor(c0, 32), e1 = __shfl_xor(c1, 32),
              e2 = __shfl_xor(c2, 32), e3 = __shfl_xor(c3, 32);
        int   j0 = __shfl_xor(k0, 32), j1 = __shfl_xor(k1, 32),
              j2 = __shfl_xor(k2, 32), j3 = __shfl_xor(k3, 32);
        INS4(e0, j0); INS4(e1, j1); INS4(e2, j2); INS4(e3, j3);
    }
    if (l < 16) {
        md_s[w][l][0] = c0; md_s[w][l][1] = c1; md_s[w][l][2] = c2; md_s[w][l][3] = c3;
        mi_s[w][l][0] = k0; mi_s[w][l][1] = k1; mi_s[w][l][2] = k2; mi_s[w][l][3] = k3;
    }
    __syncthreads();
    if ((w & 3) == 0) {
        int m16 = l & 15;
        #pragma unroll
        for (int pw = 1; pw < 4; pw++) {
            #pragma unroll
            for (int s = 0; s < 4; s++) {
                float dd = md_s[w + pw][m16][s];
                int ii = mi_s[w + pw][m16][s];
                INS4(dd, ii);
            }
        }
        const float* ob = opts + (size_t)b * 3 * NPTS;
        float t0 = 1e30f, t1 = 1e30f, t2 = 1e30f;
        int   u0 = 0x7fffffff, u1 = 0x7fffffff, u2 = 0x7fffffff;
#define INS3X(dd, ii) do { float _d = (dd); int _i = (ii);                     \
    if (LEXLT(_d, _i, t2, u2)) {                                              \
        if (LEXLT(_d, _i, t1, u1)) { t2 = t1; u2 = u1;                        \
            if (LEXLT(_d, _i, t0, u0)) { t1 = t0; u1 = u0; t0 = _d; u0 = _i; } \
            else { t1 = _d; u1 = _i; }                                        \
        } else { t2 = _d; u2 = _i; }                                          \
    } } while (0)
#define EXACTD(idx, dout) do { int _p = (idx);                                 \
    float px = ob[_p], py = ob[NPTS + _p], pz = ob[2 * NPTS + _p];             \
    float o2x = __fadd_rn(__fadd_rn(__fmul_rn(px, px), __fmul_rn(py, py)), __fmul_rn(pz, pz)); \
    float cr  = __fadd_rn(__fadd_rn(__fmul_rn(qx, px), __fmul_rn(qy, py)), __fmul_rn(qz, pz)); \
    dout = __fsub_rn(__fadd_rn(q2, o2x), __fmul_rn(2.f, cr)); } while (0)
        {
            float dx0, dx1, dx2, dx3;
            EXACTD(k0, dx0); EXACTD(k1, dx1); EXACTD(k2, dx2); EXACTD(k3, dx3);
            INS3X(dx0, k0); INS3X(dx1, k1); INS3X(dx2, k2); INS3X(dx3, k3);
        }
        if (l < 16) {
            int ids[3] = {u0, u1, u2};
            float rr[3];
            float s = 0.f;
            #pragma unroll
            for (int mm = 0; mm < 3; mm++) {
                int ii = ids[mm];
                float px = ob[ii], py = ob[NPTS + ii], pz = ob[2 * NPTS + ii];
                float dx = __fsub_rn(px, qx), dy = __fsub_rn(py, qy), dz = __fsub_rn(pz, qz);
                float dd = __fadd_rn(__fadd_rn(__fmul_rn(dx, dx), __fmul_rn(dy, dy)), __fmul_rn(dz, dz));
                float dist = sqrtf(dd);
                rr[mm] = 1.f / (__fadd_rn(dist, 1e-8f));
                s += rr[mm];
            }
            int basei = (b * NQ + qcol) * 3;
            #pragma unroll
            for (int mm = 0; mm < 3; mm++) {
                knn_idx[basei + mm] = ids[mm];
                knn_w[basei + mm]   = rr[mm] / s;
            }
        }
    }
}

// ---------------- k_tail: fused interp + r2 + r3 + r4, 32 q/block (R13 verbatim) --------
__global__ __launch_bounds__(256) void k_tail(
        const float* __restrict__ qpts, const _Float16* __restrict__ G,
        const float* __restrict__ CB, const int* __restrict__ knn_idx,
        const float* __restrict__ knn_w, const float* __restrict__ r1,
        const _Float16* __restrict__ Rw2, const float* __restrict__ rb2,
        const _Float16* __restrict__ Rw3, const float* __restrict__ rb3,
        const float* __restrict__ r4, const float* __restrict__ rb4,
        float* __restrict__ out) {
    __shared__ __align__(16) unsigned char arena[31232];
    _Float16* sH1  = (_Float16*)arena;             // [32][264] = 16896 B
    _Float16* sBst = (_Float16*)(arena + 16896);   // r2 B-stage [128][56] = 14336 B
    _Float16* sH2  = (_Float16*)arena;             // [32][136] = 8704 (aliases sH1)
    _Float16* sH3  = (_Float16*)(arena + 8704);    // [64ch][72] = 9216 (32 cols used)
    _Float16* sW3  = (_Float16*)(arena + 17920);   // r3 W-stage [64][56] = 7168
    __shared__ int   s_id[96];
    __shared__ float s_wt[96];
    __shared__ float s_qp[3][32];
    __shared__ float s_wq[3][256];
    __shared__ float s_cb[256];
    __shared__ float sw4[64];
    int t = threadIdx.x;
    int w = t >> 6, lane = t & 63;
    int m = lane & 15, quad = lane >> 4;
    int q0 = blockIdx.x * 32;
    int b = q0 >> 14;
    int qin = q0 & (NQ - 1);

    if (t < 96) {
        s_id[t] = knn_idx[q0 * 3 + t];
        s_wt[t] = knn_w[q0 * 3 + t];
        int d = t >> 5, j = t & 31;
        s_qp[d][j] = qpts[(size_t)b * 3 * NQ + d * NQ + qin + j];
    }
    s_wq[0][t] = r1[(size_t)t * 707 + 0];
    s_wq[1][t] = r1[(size_t)t * 707 + 1];
    s_wq[2][t] = r1[(size_t)t * 707 + 2];
    s_cb[t] = CB[b * 256 + t];
    if (t < 64) sw4[t] = r4[t];
    __syncthreads();

    // ---- interp: build h1 tile [32 q][256 ch] in LDS (same fmaf order as before) ----
    {
        int cg = (t & 31) * 8;
        int js = t >> 5;
        float wq0[8], wq1[8], wq2[8], cbv[8];
        #pragma unroll
        for (int u = 0; u < 8; u++) {
            wq0[u] = s_wq[0][cg + u];
            wq1[u] = s_wq[1][cg + u];
            wq2[u] = s_wq[2][cg + u];
            cbv[u] = s_cb[cg + u];
        }
        const _Float16* Gb = G + (size_t)b * NPTS * 256;
        #pragma unroll
        for (int jj = 0; jj < 4; jj++) {
            int j = js + jj * 8;
            int i0 = s_id[j * 3 + 0], i1 = s_id[j * 3 + 1], i2 = s_id[j * 3 + 2];
            float w0 = s_wt[j * 3 + 0], w1 = s_wt[j * 3 + 1], w2 = s_wt[j * 3 + 2];
            float qx = s_qp[0][j], qy = s_qp[1][j], qz = s_qp[2][j];
            h8 g0 = *(const h8*)&Gb[(size_t)i0 * 256 + cg];
            h8 g1 = *(const h8*)&Gb[(size_t)i1 * 256 + cg];
            h8 g2 = *(const h8*)&Gb[(size_t)i2 * 256 + cg];
            h8 hv;
            #pragma unroll
            for (int u = 0; u < 8; u++) {
                float acc = cbv[u];
                acc = fmaf(wq0[u], qx, acc);
                acc = fmaf(wq1[u], qy, acc);
                acc = fmaf(wq2[u], qz, acc);
                acc = fmaf(w0, (float)g0[u], acc);
                acc = fmaf(w1, (float)g1[u], acc);
                acc = fmaf(w2, (float)g2[u], acc);
                hv[u] = (_Float16)fmaxf(acc, 0.f);
            }
            *(h8*)&sH1[j * 264 + cg] = hv;
        }
    }

    // ---- r2: h2(32q x 128ch) = relu(Rw2 @ h1); A-frags straight from sH1 ----
    float h2v[2][2][4];
    {
        v4f acc[2][2];
        #pragma unroll
        for (int i = 0; i < 2; i++)
            #pragma unroll
            for (int j = 0; j < 2; j++)
                acc[i][j] = (v4f){0.f, 0.f, 0.f, 0.f};
        for (int kc = 0; kc < 256; kc += 32) {
            __syncthreads();   // first: sH1 writes; later: sBst reuse
            #pragma unroll
            for (int i = 0; i < 2; i++) {
                int e = t + i * 256;
                int r = e >> 2, p = e & 3;
                *(float4*)&sBst[r * 56 + p * 8] =
                    *(const float4*)&Rw2[(size_t)r * 256 + kc + p * 8];
            }
            __syncthreads();
            h8 af[2], bf[2];
            #pragma unroll
            for (int mt = 0; mt < 2; mt++)
                af[mt] = *(const h8*)&sH1[(mt * 16 + m) * 264 + kc + quad * 8];
            #pragma unroll
            for (int nt = 0; nt < 2; nt++)
                bf[nt] = *(const h8*)&sBst[(w * 32 + nt * 16 + m) * 56 + quad * 8];
            #pragma unroll
            for (int mt = 0; mt < 2; mt++)
                #pragma unroll
                for (int nt = 0; nt < 2; nt++)
                    acc[mt][nt] = __builtin_amdgcn_mfma_f32_16x16x32_f16(
                            af[mt], bf[nt], acc[mt][nt], 0, 0, 0);
        }
        #pragma unroll
        for (int nt = 0; nt < 2; nt++) {
            int ch = w * 32 + nt * 16 + m;
            float bb2 = rb2[ch];
            #pragma unroll
            for (int mt = 0; mt < 2; mt++)
                #pragma unroll
                for (int r = 0; r < 4; r++)
                    h2v[mt][nt][r] = fmaxf(acc[mt][nt][r] + bb2, 0.f);
        }
    }
    __syncthreads();   // all sH1 reads done -> safe to overwrite with sH2
    {
        #pragma unroll
        for (int nt = 0; nt < 2; nt++) {
            int ch = w * 32 + nt * 16 + m;
            #pragma unroll
            for (int mt = 0; mt < 2; mt++)
                #pragma unroll
                for (int r = 0; r < 4; r++) {
                    int ql = mt * 16 + quad * 4 + r;
                    sH2[ql * 136 + ch] = (_Float16)h2v[mt][nt][r];
                }
        }
    }

    // ---- r3: h3(32q x 64ch) = relu(Rw3 @ h2) ----
    float h3v[2][4];
    {
        v4f acc[2];
        acc[0] = (v4f){0.f, 0.f, 0.f, 0.f};
        acc[1] = (v4f){0.f, 0.f, 0.f, 0.f};
        for (int kc = 0; kc < 128; kc += 32) {
            __syncthreads();   // first: sH2 writes; later: sW3 reuse
            {   // 64 rows x 4 segs = 256; 1 per thread
                int r = t >> 2, p = t & 3;
                *(float4*)&sW3[r * 56 + p * 8] =
                    *(const float4*)&Rw3[(size_t)r * 128 + kc + p * 8];
            }
            __syncthreads();
            h8 af[2], bf;
            #pragma unroll
            for (int mt = 0; mt < 2; mt++)
                af[mt] = *(const h8*)&sH2[(mt * 16 + m) * 136 + kc + quad * 8];
            bf = *(const h8*)&sW3[(w * 16 + m) * 56 + quad * 8];
            #pragma unroll
            for (int mt = 0; mt < 2; mt++)
                acc[mt] = __builtin_amdgcn_mfma_f32_16x16x32_f16(
                        af[mt], bf, acc[mt], 0, 0, 0);
        }
        int ch = w * 16 + m;
        float bb3 = rb3[ch];
        #pragma unroll
        for (int mt = 0; mt < 2; mt++)
            #pragma unroll
            for (int r = 0; r < 4; r++)
                h3v[mt][r] = fmaxf(acc[mt][r] + bb3, 0.f);
    }
    __syncthreads();
    {
        int ch = w * 16 + m;
        #pragma unroll
        for (int mt = 0; mt < 2; mt++)
            #pragma unroll
            for (int r = 0; r < 4; r++) {
                int ql = mt * 16 + quad * 4 + r;
                sH3[ch * 72 + ql] = (_Float16)h3v[mt][r];
            }
    }
    __syncthreads();

    // ---- r4: out = r4 . h3 + rb4 ----
    if (t < 32) {
        float acc = rb4[0];
        #pragma unroll 16
        for (int c = 0; c < 64; c++)
            acc = fmaf((float)sH3[c * 72 + t], sw4[c], acc);
        out[q0 + t] = acc;
    }
}

extern "C" void kernel_launch(void* const* d_in, const int* in_sizes, int n_in,
                              void* d_out, int out_size, void* d_ws, size_t ws_size,
                              hipStream_t stream) {
    const float* opts = (const float*)d_in[0];
    const float* qpts = (const float*)d_in[1];
    const float* w1  = (const float*)d_in[2];
    const float* b1  = (const float*)d_in[3];
    const float* w2  = (const float*)d_in[4];
    const float* b2  = (const float*)d_in[5];
    const float* w3  = (const float*)d_in[6];
    const float* b3  = (const float*)d_in[7];
    const float* r1  = (const float*)d_in[8];
    const float* rb1 = (const float*)d_in[9];
    const float* r2  = (const float*)d_in[10];
    const float* rb2 = (const float*)d_in[11];
    const float* r3  = (const float*)d_in[12];
    const float* rb3 = (const float*)d_in[13];
    const float* r4  = (const float*)d_in[14];
    const float* rb4 = (const float*)d_in[15];
    float* out = (float*)d_out;

    unsigned char* p = (unsigned char*)d_ws;
    float* GM = (float*)p;          p += (size_t)NB * 256 * 4;
    float* CB = (float*)p;          p += (size_t)NB * 256 * 4;
    int*   IDX = (int*)p;           p += (size_t)NB * NQ * 3 * 4;
    float* WT = (float*)p;          p += (size_t)NB * NQ * 3 * 4;
    _Float16* Rw1 = (_Float16*)p;   p += (size_t)256 * FCATC * 2;
    _Float16* Rw2 = (_Float16*)p;   p += (size_t)128 * 256 * 2;
    _Float16* Rw3 = (_Float16*)p;   p += (size_t)64 * 128 * 2;
    _Float16* Ew2 = (_Float16*)p;   p += (size_t)128 * 64 * 2;
    _Float16* Ew3 = (_Float16*)p;   p += (size_t)256 * 128 * 2;
    _Float16* Atab = (_Float16*)p;  p += (size_t)NB * NPTS * 16 * 2;
    _Float16* G = (_Float16*)p;     p += (size_t)NB * NPTS * 256 * 2;   // prefetch slack

    k_pre<<<801, 256, 0, stream>>>(r1, r2, r3, w2, w3, opts,
                                   Rw1, Rw2, Rw3, Ew2, Ew3, Atab, GM);
    // fe: 32 pts/block x 256 blocks, staged pre-cast f16 weights (R13 structure)
    k_fe<<<NB * NPTS / 32, 256, 0, stream>>>(opts, w1, b1, Ew2, b2, Ew3, b3,
                                             Rw1, G, (unsigned*)GM);
    // K=16 MFMA knn, dual-chain packed-key selection; 1024 blocks x 512 thr
    k_knn<<<1024, 512, 0, stream>>>(opts, qpts, Atab, IDX, WT, r1, rb1, GM, CB);
    // tail: 32 q/block x 1024 blocks, staged pre-cast Rw2/Rw3 (R13 structure)
    k_tail<<<QTOT / 32, 256, 0, stream>>>(qpts, G, CB, IDX, WT, r1,
                                          Rw2, rb2, Rw3, rb3, r4, rb4, out);
}